// Round 1
// baseline (382.914 us; speedup 1.0000x reference)
//
#include <hip/hip_runtime.h>
#include <float.h>

// MemN2N: B=128, M=200, S=20, Q=20, H=3 hops, V=50000, D=128
// Inputs: story int32 [B,M,S], query int32 [B,Q], E f32 [4,V,D], T f32 [4,M,D]
// Output (FP32): ahat [B,V] ++ softmax(ahat) [B,V]
// R7: msum split into 4 per-table dispatches (diagnostic: surfaces hops/gemm/
//     softmax in top-5; keeps 25.6MB-at-a-time L2 locality; nt stores stop
//     msum writes evicting gather lines). GEMM retiled 128x128 acc[8][8]
//     (1.0 B LDS/MAC, was 1.5 -> LDS-bound). Softmax 2-pass online + __expf.

constexpr int Bn = 128;
constexpr int Mn = 200;
constexpr int Sn = 20;
constexpr int Qn = 20;
constexpr int Hn = 3;
constexpr int Vn = 50000;
constexpr int Dn = 128;
constexpr int CH = 100;   // fused-path chunk rows

constexpr size_t MSUM_ELEMS = (size_t)(Hn + 1) * Bn * Mn * Dn;  // 13,107,200

typedef float  f32x4 __attribute__((ext_vector_type(4)));
typedef int    i32x4 __attribute__((ext_vector_type(4)));

// ===========================================================================
// PATH 1: one table per dispatch.
// msumT[b][m][d] = sum_s Et[story[b][m][s]][d] + Tt[m][d]
// float4/thread, 32 lanes per row-slot, 8 slots per 256-thread block.
// Streaming data (story, T, msum-out) uses nontemporal to keep L2 for gathers.
// ===========================================================================
__global__ __launch_bounds__(256)
void msum_table_kernel(const int* __restrict__ story, const float4* __restrict__ Et,
                       const float4* __restrict__ Tt, float4* __restrict__ msumT) {
    int slot = threadIdx.x >> 5;          // 0..7
    int l    = threadIdx.x & 31;          // float4 index within row
    int rbm  = blockIdx.x * 8 + slot;     // b*M + m   (total 25,600)
    int m    = rbm % Mn;

    const i32x4* st4 = (const i32x4*)(story + (size_t)rbm * Sn);  // 80B aligned
    i32x4 iv0 = __builtin_nontemporal_load(st4 + 0);
    i32x4 iv1 = __builtin_nontemporal_load(st4 + 1);
    i32x4 iv2 = __builtin_nontemporal_load(st4 + 2);
    i32x4 iv3 = __builtin_nontemporal_load(st4 + 3);
    i32x4 iv4 = __builtin_nontemporal_load(st4 + 4);
    int idx[Sn] = {iv0.x, iv0.y, iv0.z, iv0.w, iv1.x, iv1.y, iv1.z, iv1.w,
                   iv2.x, iv2.y, iv2.z, iv2.w, iv3.x, iv3.y, iv3.z, iv3.w,
                   iv4.x, iv4.y, iv4.z, iv4.w};

    f32x4 acc = __builtin_nontemporal_load((const f32x4*)Tt + (size_t)m * 32 + l);
    #pragma unroll
    for (int s = 0; s < Sn; ++s) {
        float4 e = Et[(size_t)idx[s] * 32 + l];
        acc.x += e.x; acc.y += e.y; acc.z += e.z; acc.w += e.w;
    }
    __builtin_nontemporal_store(acc, (f32x4*)msumT + (size_t)rbm * 32 + l);
}

// ===========================================================================
// Hop chain from msum. grid = B x 1024 (16 waves). (unchanged this round)
// ===========================================================================
__global__ __launch_bounds__(1024)
void hops_kernel(const int* __restrict__ query, const float* __restrict__ E,
                 const float* __restrict__ msum, float* __restrict__ ufin) {
    __shared__ float u[Dn];
    __shared__ float sc[Mn];
    __shared__ float op[8 * Dn];
    __shared__ float red[16];
    __shared__ float bc[2];

    const int b    = blockIdx.x;
    const int tid  = threadIdx.x;
    const int wave = tid >> 6;
    const int lane = tid & 63;
    const int d    = tid & (Dn - 1);
    const int g    = tid >> 7;             // 0..7

    if (tid < Dn) {
        float acc = 0.f;
        const int* q = query + b * Qn;
        #pragma unroll
        for (int j = 0; j < Qn; ++j)
            acc += E[(size_t)q[j] * Dn + tid];
        u[tid] = acc;
    }
    __syncthreads();

    for (int hop = 0; hop < Hn; ++hop) {
        const float* mrow = msum + ((size_t)hop * Bn + b) * (size_t)(Mn * Dn);
        float ul = u[lane], uh = u[lane + 64];

        for (int mm = wave; mm < Mn / 2; mm += 16) {
            const float* r0 = mrow + (2 * mm) * Dn;
            const float* r1 = r0 + Dn;
            float p0 = r0[lane] * ul + r0[lane + 64] * uh;
            float p1 = r1[lane] * ul + r1[lane + 64] * uh;
            #pragma unroll
            for (int off = 32; off; off >>= 1) {
                p0 += __shfl_down(p0, off, 64);
                p1 += __shfl_down(p1, off, 64);
            }
            if (lane == 0) { sc[2 * mm] = p0; sc[2 * mm + 1] = p1; }
        }
        __syncthreads();

        float v = (tid < Mn) ? sc[tid] : -FLT_MAX;
        float mx = v;
        #pragma unroll
        for (int off = 32; off; off >>= 1) mx = fmaxf(mx, __shfl_down(mx, off, 64));
        if (lane == 0) red[wave] = mx;
        __syncthreads();
        if (tid == 0) {
            float m0 = red[0];
            #pragma unroll
            for (int i = 1; i < 16; ++i) m0 = fmaxf(m0, red[i]);
            bc[0] = m0;
        }
        __syncthreads();
        float rmax = bc[0];
        float e = (tid < Mn) ? expf(v - rmax) : 0.f;
        float sm = e;
        #pragma unroll
        for (int off = 32; off; off >>= 1) sm += __shfl_down(sm, off, 64);
        if (lane == 0) red[wave] = sm;
        __syncthreads();
        if (tid == 0) {
            float s = 0.f;
            #pragma unroll
            for (int i = 0; i < 16; ++i) s += red[i];
            bc[1] = s;
        }
        __syncthreads();
        float inv = 1.f / bc[1];
        if (tid < Mn) sc[tid] = e * inv;
        __syncthreads();

        const float* crow = msum + ((size_t)(hop + 1) * Bn + b) * (size_t)(Mn * Dn);
        float acc = 0.f;
        for (int m = g; m < Mn; m += 8)
            acc += sc[m] * crow[m * Dn + d];
        op[g * Dn + d] = acc;
        __syncthreads();
        if (tid < Dn) {
            float s = 0.f;
            #pragma unroll
            for (int i = 0; i < 8; ++i) s += op[i * Dn + tid];
            u[tid] += s;
        }
        __syncthreads();
    }
    if (tid < Dn) ufin[b * Dn + tid] = u[tid];
}

// ===========================================================================
// PATH 2 (no workspace, fallback): fused hops — unchanged.
// ===========================================================================
__global__ __launch_bounds__(1024)
void hops_fused_kernel(const int* __restrict__ story, const int* __restrict__ query,
                       const float* __restrict__ E, const float* __restrict__ T,
                       float* __restrict__ ufin) {
    __shared__ __align__(16) float tile[CH * Dn];
    __shared__ float u[Dn];
    __shared__ float sc[Mn];
    __shared__ float op[8 * Dn];
    __shared__ float red[16];
    __shared__ float bc[2];

    const int b    = blockIdx.x;
    const int tid  = threadIdx.x;
    const int wave = tid >> 6;
    const int lane = tid & 63;
    const int d    = tid & (Dn - 1);
    const int g    = tid >> 7;
    const int slot = tid >> 5;
    const int l    = tid & 31;
    const int* st  = story + b * (Mn * Sn);

    if (tid < Dn) {
        float acc = 0.f;
        const int* q = query + b * Qn;
        #pragma unroll
        for (int j = 0; j < Qn; ++j)
            acc += E[(size_t)q[j] * Dn + tid];
        u[tid] = acc;
    }

    auto build = [&](int t, int base) {
        const float4* Et = (const float4*)(E) + (size_t)t * Vn * 32;
        const float4* Tt = (const float4*)(T) + (size_t)t * Mn * 32;
        for (int m = base + slot; m < base + CH; m += 32) {
            const int* sm = st + m * Sn;
            float4 acc = Tt[(size_t)m * 32 + l];
            #pragma unroll
            for (int s = 0; s < Sn; ++s) {
                float4 e = Et[(size_t)sm[s] * 32 + l];
                acc.x += e.x; acc.y += e.y; acc.z += e.z; acc.w += e.w;
            }
            ((float4*)tile)[(m - base) * 32 + l] = acc;
        }
    };
    auto scores = [&](int base) {
        for (int m = base + wave; m < base + CH; m += 16) {
            float p = tile[(m - base) * Dn + lane]      * u[lane]
                    + tile[(m - base) * Dn + lane + 64] * u[lane + 64];
            #pragma unroll
            for (int off = 32; off; off >>= 1) p += __shfl_down(p, off, 64);
            if (lane == 0) sc[m] = p;
        }
    };

    for (int hop = 0; hop < Hn; ++hop) {
        if (hop == 0) {
            build(0, 0);  __syncthreads(); scores(0);  __syncthreads();
            build(0, CH); __syncthreads(); scores(CH); __syncthreads();
        } else {
            scores(CH); __syncthreads();
            build(hop, 0); __syncthreads(); scores(0); __syncthreads();
        }

        float v = (tid < Mn) ? sc[tid] : -FLT_MAX;
        float mx = v;
        #pragma unroll
        for (int off = 32; off; off >>= 1) mx = fmaxf(mx, __shfl_down(mx, off, 64));
        if (lane == 0) red[wave] = mx;
        __syncthreads();
        if (tid == 0) {
            float m0 = red[0];
            #pragma unroll
            for (int i = 1; i < 16; ++i) m0 = fmaxf(m0, red[i]);
            bc[0] = m0;
        }
        __syncthreads();
        float rmax = bc[0];
        float e = (tid < Mn) ? expf(v - rmax) : 0.f;
        float sm = e;
        #pragma unroll
        for (int off = 32; off; off >>= 1) sm += __shfl_down(sm, off, 64);
        if (lane == 0) red[wave] = sm;
        __syncthreads();
        if (tid == 0) {
            float s = 0.f;
            #pragma unroll
            for (int i = 0; i < 16; ++i) s += red[i];
            bc[1] = s;
        }
        __syncthreads();
        float inv = 1.f / bc[1];
        if (tid < Mn) sc[tid] = e * inv;

        float oacc = 0.f;
        build(hop + 1, 0);
        __syncthreads();
        for (int m = g; m < CH; m += 8)
            oacc += sc[m] * tile[m * Dn + d];
        __syncthreads();
        build(hop + 1, CH);
        __syncthreads();
        for (int m = CH + g; m < 2 * CH; m += 8)
            oacc += sc[m] * tile[(m - CH) * Dn + d];
        op[g * Dn + d] = oacc;
        __syncthreads();
        if (tid < Dn) {
            float s = 0.f;
            #pragma unroll
            for (int i = 0; i < 8; ++i) s += op[i * Dn + tid];
            u[tid] += s;
        }
        __syncthreads();
    }

    if (tid < Dn) ufin[b * Dn + tid] = u[tid];
}

// ===========================================================================
// ahat GEMM: C[b,v] = sum_d U[b,d]*E3[v,d].  M=128, N=50000, K=128.
// R7: tile 128b x 128v (391 blocks), 256 threads (16 tr x 16 tc), acc[8][8].
// Per k-step/thread: 4x ds_read_b128 (64B) for 64 MACs -> 1.0 B/MAC = 128 B/cyc
// LDS demand (was 1.5 B/MAC = 192 B/cyc, over 128 B/cyc LDS peak).
// Gap layout col' = col + 4*(col>>5): fragment b128 reads 2-way (free, m136).
// ===========================================================================
constexpr int KC   = 32;
constexpr int LSTR = 140;   // 128 cols + gaps (max col' = 127+12 = 139)
__device__ __forceinline__ int ldsCol(int c) { return c + 4 * (c >> 5); }

__global__ __launch_bounds__(256)
void ahat_gemm_kernel(const float* __restrict__ E, const float* __restrict__ ufin,
                      float* __restrict__ out) {
    __shared__ float uA[KC * LSTR];
    __shared__ float eB[KC * LSTR];
    const float* E3 = E + (size_t)Hn * Vn * Dn;

    const int tid   = threadIdx.x;
    const int tr    = tid & 15;        // b-group (8 rows each)
    const int tc    = tid >> 4;        // v-group (8 cols each)
    const int vbase = blockIdx.x * 128;

    const int f4 = tid & 7;            // k-float4 within chunk
    const int rr = tid >> 3;           // staging row 0..31

    float acc[8][8];
    #pragma unroll
    for (int i = 0; i < 8; ++i)
        #pragma unroll
        for (int j = 0; j < 8; ++j) acc[i][j] = 0.f;

    for (int kb = 0; kb < Dn; kb += KC) {
        #pragma unroll
        for (int i = 0; i < 4; ++i) {
            int r   = rr + 32 * i;
            int col = ldsCol(r);
            float4 uv = *(const float4*)(ufin + (size_t)r * Dn + kb + f4 * 4);
            uA[(f4 * 4 + 0) * LSTR + col] = uv.x;
            uA[(f4 * 4 + 1) * LSTR + col] = uv.y;
            uA[(f4 * 4 + 2) * LSTR + col] = uv.z;
            uA[(f4 * 4 + 3) * LSTR + col] = uv.w;
            int vg = vbase + r; if (vg > Vn - 1) vg = Vn - 1;
            float4 ev = *(const float4*)(E3 + (size_t)vg * Dn + kb + f4 * 4);
            eB[(f4 * 4 + 0) * LSTR + col] = ev.x;
            eB[(f4 * 4 + 1) * LSTR + col] = ev.y;
            eB[(f4 * 4 + 2) * LSTR + col] = ev.z;
            eB[(f4 * 4 + 3) * LSTR + col] = ev.w;
        }
        __syncthreads();
        const int ca = ldsCol(tr * 8);
        const int cb = ldsCol(tc * 8);
        #pragma unroll 2
        for (int k = 0; k < KC; ++k) {
            float4 a0 = *(const float4*)&uA[k * LSTR + ca];
            float4 a1 = *(const float4*)&uA[k * LSTR + ca + 4];
            float4 b0 = *(const float4*)&eB[k * LSTR + cb];
            float4 b1 = *(const float4*)&eB[k * LSTR + cb + 4];
            float av[8] = {a0.x, a0.y, a0.z, a0.w, a1.x, a1.y, a1.z, a1.w};
            float bv[8] = {b0.x, b0.y, b0.z, b0.w, b1.x, b1.y, b1.z, b1.w};
            #pragma unroll
            for (int i = 0; i < 8; ++i)
                #pragma unroll
                for (int j = 0; j < 8; ++j)
                    acc[i][j] += av[i] * bv[j];
        }
        __syncthreads();
    }

    const int v0 = vbase + tc * 8;     // Vn % 8 == 0: group fully valid or fully out
    if (v0 < Vn) {
        #pragma unroll
        for (int i = 0; i < 8; ++i) {
            int bb = tr * 8 + i;
            *(float4*)(out + (size_t)bb * Vn + v0) =
                make_float4(acc[i][0], acc[i][1], acc[i][2], acc[i][3]);
            *(float4*)(out + (size_t)bb * Vn + v0 + 4) =
                make_float4(acc[i][4], acc[i][5], acc[i][6], acc[i][7]);
        }
    }
}

// ===========================================================================
// Row softmax over V=50000 (fp32), float4. grid = B x 1024.
// R7: 2-pass online (max+sum fused with running rescale), __expf.
// Traffic 4 -> 3 passes: 102 MB -> 77 MB.
// ===========================================================================
__global__ __launch_bounds__(1024)
void softmax_kernel(const float* __restrict__ ahat, float* __restrict__ osm) {
    __shared__ float redm[16];
    __shared__ float reds[16];
    __shared__ float bc2[2];

    int b    = blockIdx.x;
    int tid  = threadIdx.x;
    int wave = tid >> 6;
    int lane = tid & 63;

    const float4* row  = (const float4*)(ahat + (size_t)b * Vn);
    float4*       orow = (float4*)(osm + (size_t)b * Vn);
    constexpr int N4 = Vn / 4;

    // pass A: online (max, sum-exp)
    float m = -FLT_MAX, s = 0.f;
    for (int v = tid; v < N4; v += 1024) {
        float4 x = row[v];
        float cm = fmaxf(fmaxf(x.x, x.y), fmaxf(x.z, x.w));
        if (cm > m) { s *= __expf(m - cm); m = cm; }
        s += __expf(x.x - m) + __expf(x.y - m) + __expf(x.z - m) + __expf(x.w - m);
    }
    #pragma unroll
    for (int off = 32; off; off >>= 1) {
        float mo = __shfl_down(m, off, 64);
        float so = __shfl_down(s, off, 64);
        float nm = fmaxf(m, mo);
        s = s * __expf(m - nm) + so * __expf(mo - nm);
        m = nm;
    }
    if (lane == 0) { redm[wave] = m; reds[wave] = s; }
    __syncthreads();
    if (tid == 0) {
        float M = redm[0];
        #pragma unroll
        for (int i = 1; i < 16; ++i) M = fmaxf(M, redm[i]);
        float S = 0.f;
        #pragma unroll
        for (int i = 0; i < 16; ++i) S += reds[i] * __expf(redm[i] - M);
        bc2[0] = M; bc2[1] = 1.f / S;
    }
    __syncthreads();
    float rmax = bc2[0];
    float inv  = bc2[1];

    // pass B: normalize + write
    for (int v = tid; v < N4; v += 1024) {
        float4 x = row[v];
        orow[v] = make_float4(__expf(x.x - rmax) * inv, __expf(x.y - rmax) * inv,
                              __expf(x.z - rmax) * inv, __expf(x.w - rmax) * inv);
    }
}

// ===========================================================================
extern "C" void kernel_launch(void* const* d_in, const int* in_sizes, int n_in,
                              void* d_out, int out_size, void* d_ws, size_t ws_size,
                              hipStream_t stream) {
    const int*   story = (const int*)d_in[0];
    const int*   query = (const int*)d_in[1];
    const float* E     = (const float*)d_in[2];
    const float* T     = (const float*)d_in[3];

    float* out  = (float*)d_out;
    float* ufin = out + (size_t)Bn * Vn;   // staged in dead second output half

    if (ws_size >= MSUM_ELEMS * sizeof(float)) {
        float* msum = (float*)d_ws;
        for (int t = 0; t < Hn + 1; ++t) {
            msum_table_kernel<<<Bn * Mn / 8, 256, 0, stream>>>(
                story,
                (const float4*)(E + (size_t)t * Vn * Dn),
                (const float4*)(T + (size_t)t * Mn * Dn),
                (float4*)(msum + (size_t)t * Bn * Mn * Dn));
        }
        hops_kernel<<<Bn, 1024, 0, stream>>>(query, E, msum, ufin);
    } else {
        hops_fused_kernel<<<Bn, 1024, 0, stream>>>(story, query, E, T, ufin);
    }
    ahat_gemm_kernel<<<(Vn + 127) / 128, 256, 0, stream>>>(E, ufin, out);
    softmax_kernel<<<Bn, 1024, 0, stream>>>(out, out + (size_t)Bn * Vn);
}

// Round 3
// 341.311 us; speedup vs baseline: 1.1219x; 1.1219x over previous
//
#include <hip/hip_runtime.h>
#include <float.h>

// MemN2N: B=128, M=200, S=20, Q=20, H=3 hops, V=50000, D=128
// Inputs: story int32 [B,M,S], query int32 [B,Q], E f32 [4,V,D], T f32 [4,M,D]
// Output (FP32): ahat [B,V] ++ softmax(ahat) [B,V]
// R9 == R8 resubmit (container infra failure; no counters came back).
//     msum: R6 combined kernel (measured 137-140us).
//     hops: score phase 4-row ILP via float2 (4 shfl chains in flight).
//     softmax: gemm epilogue emits per-(row,vtile) {max,expsum} partials to
//     ws; merge+normalize kernel at grid (10,128) (BW-bound).

constexpr int Bn = 128;
constexpr int Mn = 200;
constexpr int Sn = 20;
constexpr int Qn = 20;
constexpr int Hn = 3;
constexpr int Vn = 50000;
constexpr int Dn = 128;
constexpr int CH = 100;   // fused-path chunk rows

constexpr int GTILE = 128;                       // gemm v-tile width
constexpr int NT    = (Vn + GTILE - 1) / GTILE;  // 391 tiles
constexpr int SMCHK = 10;                        // softmax chunks per row

constexpr size_t MSUM_ELEMS = (size_t)(Hn + 1) * Bn * Mn * Dn;  // 13,107,200
constexpr size_t SMWS_ELEMS = (size_t)NT * Bn * 2;              // 100,096

// ===========================================================================
// PATH 1: msum[t][b][m][d] = sum_s E[t][story[b][m][s]][d] + T[t][m][d]
// (R6 kernel.) float4/thread, 32 lanes per row-slot, 8 slots per 256-thr block.
// ===========================================================================
__global__ __launch_bounds__(256)
void msum_kernel(const int* __restrict__ story, const float* __restrict__ E,
                 const float* __restrict__ T, float* __restrict__ msum) {
    int slot = threadIdx.x >> 5;          // 0..7
    int l    = threadIdx.x & 31;          // float4 index within row
    int row  = blockIdx.x * 8 + slot;     // t*B*M + b*M + m   (total 102,400)
    int t    = row / (Bn * Mn);
    int rem  = row - t * (Bn * Mn);
    int b    = rem / Mn;
    int m    = rem - b * Mn;

    const int* st = story + (b * Mn + m) * Sn;
    const float4* Tv = (const float4*)(T) + (size_t)(t * Mn + m) * 32;
    const float4* Et = (const float4*)(E) + (size_t)t * Vn * 32;

    float4 acc = Tv[l];
    #pragma unroll
    for (int s = 0; s < Sn; ++s) {
        float4 e = Et[(size_t)st[s] * 32 + l];
        acc.x += e.x; acc.y += e.y; acc.z += e.z; acc.w += e.w;
    }
    ((float4*)msum)[(size_t)row * 32 + l] = acc;
}

// ===========================================================================
// Hop chain from msum. grid = B x 1024 (16 waves).
// Score phase: each wave reduces FOUR m-rows per iteration (float2 loads,
// 4 interleaved shfl chains hide each other's DS latency).
// ===========================================================================
__global__ __launch_bounds__(1024)
void hops_kernel(const int* __restrict__ query, const float* __restrict__ E,
                 const float* __restrict__ msum, float* __restrict__ ufin) {
    __shared__ __align__(16) float u[Dn];
    __shared__ float sc[Mn];
    __shared__ float op[8 * Dn];
    __shared__ float red[16];
    __shared__ float bc[2];

    const int b    = blockIdx.x;
    const int tid  = threadIdx.x;
    const int wave = tid >> 6;
    const int lane = tid & 63;
    const int d    = tid & (Dn - 1);
    const int g    = tid >> 7;             // 0..7

    if (tid < Dn) {
        float acc = 0.f;
        const int* q = query + b * Qn;
        #pragma unroll
        for (int j = 0; j < Qn; ++j)
            acc += E[(size_t)q[j] * Dn + tid];
        u[tid] = acc;
    }
    __syncthreads();

    for (int hop = 0; hop < Hn; ++hop) {
        const float* mrow = msum + ((size_t)hop * Bn + b) * (size_t)(Mn * Dn);
        float2 u2 = *(const float2*)(u + 2 * lane);

        // scores: wave handles quad (4q..4q+3), q = wave, wave+16, ...
        for (int q = wave; q < Mn / 4; q += 16) {
            const float* r = mrow + (size_t)q * 4 * Dn;
            float2 a0 = *(const float2*)(r + 0 * Dn + 2 * lane);
            float2 a1 = *(const float2*)(r + 1 * Dn + 2 * lane);
            float2 a2 = *(const float2*)(r + 2 * Dn + 2 * lane);
            float2 a3 = *(const float2*)(r + 3 * Dn + 2 * lane);
            float p0 = a0.x * u2.x + a0.y * u2.y;
            float p1 = a1.x * u2.x + a1.y * u2.y;
            float p2 = a2.x * u2.x + a2.y * u2.y;
            float p3 = a3.x * u2.x + a3.y * u2.y;
            #pragma unroll
            for (int off = 32; off; off >>= 1) {
                p0 += __shfl_down(p0, off, 64);
                p1 += __shfl_down(p1, off, 64);
                p2 += __shfl_down(p2, off, 64);
                p3 += __shfl_down(p3, off, 64);
            }
            if (lane == 0) {
                sc[4 * q + 0] = p0; sc[4 * q + 1] = p1;
                sc[4 * q + 2] = p2; sc[4 * q + 3] = p3;
            }
        }
        __syncthreads();

        // softmax over sc[0..200)
        float v = (tid < Mn) ? sc[tid] : -FLT_MAX;
        float mx = v;
        #pragma unroll
        for (int off = 32; off; off >>= 1) mx = fmaxf(mx, __shfl_down(mx, off, 64));
        if (lane == 0) red[wave] = mx;
        __syncthreads();
        if (tid == 0) {
            float m0 = red[0];
            #pragma unroll
            for (int i = 1; i < 16; ++i) m0 = fmaxf(m0, red[i]);
            bc[0] = m0;
        }
        __syncthreads();
        float rmax = bc[0];
        float e = (tid < Mn) ? __expf(v - rmax) : 0.f;
        float sm = e;
        #pragma unroll
        for (int off = 32; off; off >>= 1) sm += __shfl_down(sm, off, 64);
        if (lane == 0) red[wave] = sm;
        __syncthreads();
        if (tid == 0) {
            float s = 0.f;
            #pragma unroll
            for (int i = 0; i < 16; ++i) s += red[i];
            bc[1] = s;
        }
        __syncthreads();
        float inv = 1.f / bc[1];
        if (tid < Mn) sc[tid] = e * inv;
        __syncthreads();

        // o[d] = sum_m proba[m] * c[m][d]; u += o
        const float* crow = msum + ((size_t)(hop + 1) * Bn + b) * (size_t)(Mn * Dn);
        float acc = 0.f;
        for (int m = g; m < Mn; m += 8)
            acc += sc[m] * crow[m * Dn + d];
        op[g * Dn + d] = acc;
        __syncthreads();
        if (tid < Dn) {
            float s = 0.f;
            #pragma unroll
            for (int i = 0; i < 8; ++i) s += op[i * Dn + tid];
            u[tid] += s;
        }
        __syncthreads();
    }
    if (tid < Dn) ufin[b * Dn + tid] = u[tid];
}

// ===========================================================================
// PATH 2 (no workspace, fallback): fused hops — unchanged.
// ===========================================================================
__global__ __launch_bounds__(1024)
void hops_fused_kernel(const int* __restrict__ story, const int* __restrict__ query,
                       const float* __restrict__ E, const float* __restrict__ T,
                       float* __restrict__ ufin) {
    __shared__ __align__(16) float tile[CH * Dn];
    __shared__ float u[Dn];
    __shared__ float sc[Mn];
    __shared__ float op[8 * Dn];
    __shared__ float red[16];
    __shared__ float bc[2];

    const int b    = blockIdx.x;
    const int tid  = threadIdx.x;
    const int wave = tid >> 6;
    const int lane = tid & 63;
    const int d    = tid & (Dn - 1);
    const int g    = tid >> 7;
    const int slot = tid >> 5;
    const int l    = tid & 31;
    const int* st  = story + b * (Mn * Sn);

    if (tid < Dn) {
        float acc = 0.f;
        const int* q = query + b * Qn;
        #pragma unroll
        for (int j = 0; j < Qn; ++j)
            acc += E[(size_t)q[j] * Dn + tid];
        u[tid] = acc;
    }

    auto build = [&](int t, int base) {
        const float4* Et = (const float4*)(E) + (size_t)t * Vn * 32;
        const float4* Tt = (const float4*)(T) + (size_t)t * Mn * 32;
        for (int m = base + slot; m < base + CH; m += 32) {
            const int* sm = st + m * Sn;
            float4 acc = Tt[(size_t)m * 32 + l];
            #pragma unroll
            for (int s = 0; s < Sn; ++s) {
                float4 e = Et[(size_t)sm[s] * 32 + l];
                acc.x += e.x; acc.y += e.y; acc.z += e.z; acc.w += e.w;
            }
            ((float4*)tile)[(m - base) * 32 + l] = acc;
        }
    };
    auto scores = [&](int base) {
        for (int m = base + wave; m < base + CH; m += 16) {
            float p = tile[(m - base) * Dn + lane]      * u[lane]
                    + tile[(m - base) * Dn + lane + 64] * u[lane + 64];
            #pragma unroll
            for (int off = 32; off; off >>= 1) p += __shfl_down(p, off, 64);
            if (lane == 0) sc[m] = p;
        }
    };

    for (int hop = 0; hop < Hn; ++hop) {
        if (hop == 0) {
            build(0, 0);  __syncthreads(); scores(0);  __syncthreads();
            build(0, CH); __syncthreads(); scores(CH); __syncthreads();
        } else {
            scores(CH); __syncthreads();
            build(hop, 0); __syncthreads(); scores(0); __syncthreads();
        }

        float v = (tid < Mn) ? sc[tid] : -FLT_MAX;
        float mx = v;
        #pragma unroll
        for (int off = 32; off; off >>= 1) mx = fmaxf(mx, __shfl_down(mx, off, 64));
        if (lane == 0) red[wave] = mx;
        __syncthreads();
        if (tid == 0) {
            float m0 = red[0];
            #pragma unroll
            for (int i = 1; i < 16; ++i) m0 = fmaxf(m0, red[i]);
            bc[0] = m0;
        }
        __syncthreads();
        float rmax = bc[0];
        float e = (tid < Mn) ? __expf(v - rmax) : 0.f;
        float sm = e;
        #pragma unroll
        for (int off = 32; off; off >>= 1) sm += __shfl_down(sm, off, 64);
        if (lane == 0) red[wave] = sm;
        __syncthreads();
        if (tid == 0) {
            float s = 0.f;
            #pragma unroll
            for (int i = 0; i < 16; ++i) s += red[i];
            bc[1] = s;
        }
        __syncthreads();
        float inv = 1.f / bc[1];
        if (tid < Mn) sc[tid] = e * inv;

        float oacc = 0.f;
        build(hop + 1, 0);
        __syncthreads();
        for (int m = g; m < CH; m += 8)
            oacc += sc[m] * tile[m * Dn + d];
        __syncthreads();
        build(hop + 1, CH);
        __syncthreads();
        for (int m = CH + g; m < 2 * CH; m += 8)
            oacc += sc[m] * tile[(m - CH) * Dn + d];
        op[g * Dn + d] = oacc;
        __syncthreads();
        if (tid < Dn) {
            float s = 0.f;
            #pragma unroll
            for (int i = 0; i < 8; ++i) s += op[i * Dn + tid];
            u[tid] += s;
        }
        __syncthreads();
    }

    if (tid < Dn) ufin[b * Dn + tid] = u[tid];
}

// ===========================================================================
// ahat GEMM: C[b,v] = sum_d U[b,d]*E3[v,d].  M=128, N=50000, K=128.
// Tile 128b x 128v (391 blocks), 256 threads (16 tr x 16 tc), acc[8][8].
// Epilogue: per-(row, vtile) softmax partials {max, expsum} -> ws2
// (reuses uA/eB LDS; invalid padded cols contribute -FLT_MAX/0 = no-op).
// ===========================================================================
constexpr int KC   = 32;
constexpr int LSTR = 140;   // 128 cols + gaps
__device__ __forceinline__ int ldsCol(int c) { return c + 4 * (c >> 5); }

__global__ __launch_bounds__(256)
void ahat_gemm_kernel(const float* __restrict__ E, const float* __restrict__ ufin,
                      float* __restrict__ out, float* __restrict__ ws2) {
    __shared__ __align__(16) float uA[KC * LSTR];
    __shared__ __align__(16) float eB[KC * LSTR];
    const float* E3 = E + (size_t)Hn * Vn * Dn;

    const int tid   = threadIdx.x;
    const int tr    = tid & 15;        // b-group (8 rows each)
    const int tc    = tid >> 4;        // v-group (8 cols each)
    const int vbase = blockIdx.x * GTILE;

    const int f4 = tid & 7;            // k-float4 within chunk
    const int rr = tid >> 3;           // staging row 0..31

    float acc[8][8];
    #pragma unroll
    for (int i = 0; i < 8; ++i)
        #pragma unroll
        for (int j = 0; j < 8; ++j) acc[i][j] = 0.f;

    for (int kb = 0; kb < Dn; kb += KC) {
        #pragma unroll
        for (int i = 0; i < 4; ++i) {
            int r   = rr + 32 * i;
            int col = ldsCol(r);
            float4 uv = *(const float4*)(ufin + (size_t)r * Dn + kb + f4 * 4);
            uA[(f4 * 4 + 0) * LSTR + col] = uv.x;
            uA[(f4 * 4 + 1) * LSTR + col] = uv.y;
            uA[(f4 * 4 + 2) * LSTR + col] = uv.z;
            uA[(f4 * 4 + 3) * LSTR + col] = uv.w;
        }
        #pragma unroll
        for (int i = 0; i < 4; ++i) {
            int r  = rr + 32 * i;
            int vg = vbase + r; if (vg > Vn - 1) vg = Vn - 1;
            int col = ldsCol(r);
            float4 ev = *(const float4*)(E3 + (size_t)vg * Dn + kb + f4 * 4);
            eB[(f4 * 4 + 0) * LSTR + col] = ev.x;
            eB[(f4 * 4 + 1) * LSTR + col] = ev.y;
            eB[(f4 * 4 + 2) * LSTR + col] = ev.z;
            eB[(f4 * 4 + 3) * LSTR + col] = ev.w;
        }
        __syncthreads();
        const int ca = ldsCol(tr * 8);
        const int cb = ldsCol(tc * 8);
        #pragma unroll 2
        for (int k = 0; k < KC; ++k) {
            float4 a0 = *(const float4*)&uA[k * LSTR + ca];
            float4 a1 = *(const float4*)&uA[k * LSTR + ca + 4];
            float4 b0 = *(const float4*)&eB[k * LSTR + cb];
            float4 b1 = *(const float4*)&eB[k * LSTR + cb + 4];
            float av[8] = {a0.x, a0.y, a0.z, a0.w, a1.x, a1.y, a1.z, a1.w};
            float bv[8] = {b0.x, b0.y, b0.z, b0.w, b1.x, b1.y, b1.z, b1.w};
            #pragma unroll
            for (int i = 0; i < 8; ++i)
                #pragma unroll
                for (int j = 0; j < 8; ++j)
                    acc[i][j] += av[i] * bv[j];
        }
        __syncthreads();
    }

    const int  v0    = vbase + tc * 8;   // group fully valid or fully out (80%8==0)
    const bool valid = v0 < Vn;
    if (valid) {
        #pragma unroll
        for (int i = 0; i < 8; ++i) {
            int bb = tr * 8 + i;
            *(float4*)(out + (size_t)bb * Vn + v0) =
                make_float4(acc[i][0], acc[i][1], acc[i][2], acc[i][3]);
            *(float4*)(out + (size_t)bb * Vn + v0 + 4) =
                make_float4(acc[i][4], acc[i][5], acc[i][6], acc[i][7]);
        }
    }

    if (ws2) {
        // per-thread {max, expsum} over its 8 cols, for each of its 8 rows
        #pragma unroll
        for (int i = 0; i < 8; ++i) {
            float tm = -FLT_MAX, ts = 0.f;
            if (valid) {
                #pragma unroll
                for (int j = 0; j < 8; ++j) tm = fmaxf(tm, acc[i][j]);
                #pragma unroll
                for (int j = 0; j < 8; ++j) ts += __expf(acc[i][j] - tm);
            }
            uA[tc * 128 + tr * 8 + i] = tm;
            eB[tc * 128 + tr * 8 + i] = ts;
        }
        __syncthreads();
        if (tid < Bn) {
            float M = -FLT_MAX;
            #pragma unroll
            for (int t = 0; t < 16; ++t) M = fmaxf(M, uA[t * 128 + tid]);
            float S = 0.f;
            #pragma unroll
            for (int t = 0; t < 16; ++t)
                S += eB[t * 128 + tid] * __expf(uA[t * 128 + tid] - M);
            float2* w = (float2*)ws2;
            w[(size_t)blockIdx.x * Bn + tid] = make_float2(M, S);
        }
    }
}

// ===========================================================================
// Softmax merge + normalize. grid = (SMCHK, B) x 256. Reads per-tile partials
// (NT pairs per row), merges to global {M, 1/S}, normalizes its V-chunk.
// ===========================================================================
__global__ __launch_bounds__(256)
void softmax_merge_kernel(const float* __restrict__ ahat, const float* __restrict__ ws2,
                          float* __restrict__ osm) {
    __shared__ float redm[4], reds[4];
    __shared__ float bcM, bcI;

    const int ck   = blockIdx.x;
    const int b    = blockIdx.y;
    const int tid  = threadIdx.x;
    const int wave = tid >> 6;
    const int lane = tid & 63;

    float m = -FLT_MAX, s = 0.f;
    const float2* w = (const float2*)ws2;
    for (int i = tid; i < NT; i += 256) {
        float2 p = w[(size_t)i * Bn + b];
        float nm = fmaxf(m, p.x);
        s = s * __expf(m - nm) + p.y * __expf(p.x - nm);
        m = nm;
    }
    #pragma unroll
    for (int off = 32; off; off >>= 1) {
        float mo = __shfl_down(m, off, 64);
        float so = __shfl_down(s, off, 64);
        float nm = fmaxf(m, mo);
        s = s * __expf(m - nm) + so * __expf(mo - nm);
        m = nm;
    }
    if (lane == 0) { redm[wave] = m; reds[wave] = s; }
    __syncthreads();
    if (tid == 0) {
        float M = redm[0];
        #pragma unroll
        for (int i = 1; i < 4; ++i) M = fmaxf(M, redm[i]);
        float S = 0.f;
        #pragma unroll
        for (int i = 0; i < 4; ++i) S += reds[i] * __expf(redm[i] - M);
        bcM = M; bcI = 1.f / S;
    }
    __syncthreads();
    const float M   = bcM;
    const float inv = bcI;

    constexpr int C4 = Vn / SMCHK / 4;   // 1250 float4 per chunk
    const float4* row  = (const float4*)(ahat + (size_t)b * Vn) + (size_t)ck * C4;
    float4*       orow = (float4*)(osm + (size_t)b * Vn) + (size_t)ck * C4;
    for (int v = tid; v < C4; v += 256) {
        float4 x = row[v];
        orow[v] = make_float4(__expf(x.x - M) * inv, __expf(x.y - M) * inv,
                              __expf(x.z - M) * inv, __expf(x.w - M) * inv);
    }
}

// ===========================================================================
// Fallback row softmax over V=50000 (fp32), 2-pass online. grid = B x 1024.
// ===========================================================================
__global__ __launch_bounds__(1024)
void softmax_kernel(const float* __restrict__ ahat, float* __restrict__ osm) {
    __shared__ float redm[16];
    __shared__ float reds[16];
    __shared__ float bc2[2];

    int b    = blockIdx.x;
    int tid  = threadIdx.x;
    int wave = tid >> 6;
    int lane = tid & 63;

    const float4* row  = (const float4*)(ahat + (size_t)b * Vn);
    float4*       orow = (float4*)(osm + (size_t)b * Vn);
    constexpr int N4 = Vn / 4;

    float m = -FLT_MAX, s = 0.f;
    for (int v = tid; v < N4; v += 1024) {
        float4 x = row[v];
        float cm = fmaxf(fmaxf(x.x, x.y), fmaxf(x.z, x.w));
        if (cm > m) { s *= __expf(m - cm); m = cm; }
        s += __expf(x.x - m) + __expf(x.y - m) + __expf(x.z - m) + __expf(x.w - m);
    }
    #pragma unroll
    for (int off = 32; off; off >>= 1) {
        float mo = __shfl_down(m, off, 64);
        float so = __shfl_down(s, off, 64);
        float nm = fmaxf(m, mo);
        s = s * __expf(m - nm) + so * __expf(mo - nm);
        m = nm;
    }
    if (lane == 0) { redm[wave] = m; reds[wave] = s; }
    __syncthreads();
    if (tid == 0) {
        float M = redm[0];
        #pragma unroll
        for (int i = 1; i < 16; ++i) M = fmaxf(M, redm[i]);
        float S = 0.f;
        #pragma unroll
        for (int i = 0; i < 16; ++i) S += reds[i] * __expf(redm[i] - M);
        bc2[0] = M; bc2[1] = 1.f / S;
    }
    __syncthreads();
    float rmax = bc2[0];
    float inv  = bc2[1];

    for (int v = tid; v < N4; v += 1024) {
        float4 x = row[v];
        orow[v] = make_float4(__expf(x.x - rmax) * inv, __expf(x.y - rmax) * inv,
                              __expf(x.z - rmax) * inv, __expf(x.w - rmax) * inv);
    }
}

// ===========================================================================
extern "C" void kernel_launch(void* const* d_in, const int* in_sizes, int n_in,
                              void* d_out, int out_size, void* d_ws, size_t ws_size,
                              hipStream_t stream) {
    const int*   story = (const int*)d_in[0];
    const int*   query = (const int*)d_in[1];
    const float* E     = (const float*)d_in[2];
    const float* T     = (const float*)d_in[3];

    float* out  = (float*)d_out;
    float* ufin = out + (size_t)Bn * Vn;   // staged in dead second output half

    const bool haveMsum = ws_size >= MSUM_ELEMS * sizeof(float);
    const bool haveSm   = ws_size >= (MSUM_ELEMS + SMWS_ELEMS) * sizeof(float);
    float* msum = (float*)d_ws;
    float* ws2  = haveSm ? ((float*)d_ws + MSUM_ELEMS) : nullptr;

    if (haveMsum) {
        msum_kernel<<<(Hn + 1) * Bn * Mn / 8, 256, 0, stream>>>(story, E, T, msum);
        hops_kernel<<<Bn, 1024, 0, stream>>>(query, E, msum, ufin);
    } else {
        hops_fused_kernel<<<Bn, 1024, 0, stream>>>(story, query, E, T, ufin);
    }

    ahat_gemm_kernel<<<NT, 256, 0, stream>>>(E, ufin, out, ws2);

    if (ws2) {
        softmax_merge_kernel<<<dim3(SMCHK, Bn), 256, 0, stream>>>(
            out, ws2, out + (size_t)Bn * Vn);
    } else {
        softmax_kernel<<<Bn, 1024, 0, stream>>>(out, out + (size_t)Bn * Vn);
    }
}

// Round 4
// 323.071 us; speedup vs baseline: 1.1852x; 1.0565x over previous
//
#include <hip/hip_runtime.h>
#include <float.h>

// MemN2N: B=128, M=200, S=20, Q=20, H=3 hops, V=50000, D=128
// Inputs: story int32 [B,M,S], query int32 [B,Q], E f32 [4,V,D], T f32 [4,M,D]
// Output (FP32): ahat [B,V] ++ softmax(ahat) [B,V]
// R10: hops rewritten latency-first: per-b LDS panel (200x128, stride 130 ->
//      2-way bank alias = free), batched-13 staging loads (1 latency exposure),
//      shuffle-free scores (per-thread LDS dots over (m, d-quarter)), c-phase
//      from the same panel (table staged once: C for hop h = A for hop h+1).
//      msum / gemm+partials / merge unchanged from R9 (341.3us).

constexpr int Bn = 128;
constexpr int Mn = 200;
constexpr int Sn = 20;
constexpr int Qn = 20;
constexpr int Hn = 3;
constexpr int Vn = 50000;
constexpr int Dn = 128;
constexpr int CH = 100;   // fused-path chunk rows

constexpr int GTILE = 128;                       // gemm v-tile width
constexpr int NT    = (Vn + GTILE - 1) / GTILE;  // 391 tiles
constexpr int SMCHK = 10;                        // softmax chunks per row

constexpr int TSTR = 130;   // hops LDS panel stride (2-way bank alias = free)

constexpr size_t MSUM_ELEMS = (size_t)(Hn + 1) * Bn * Mn * Dn;  // 13,107,200
constexpr size_t SMWS_ELEMS = (size_t)NT * Bn * 2;              // 100,096

// ===========================================================================
// PATH 1: msum[t][b][m][d] = sum_s E[t][story[b][m][s]][d] + T[t][m][d]
// (R6 kernel, measured 136-140us.) float4/thread, 32 lanes per row-slot,
// 8 slots per 256-thread block.
// ===========================================================================
__global__ __launch_bounds__(256)
void msum_kernel(const int* __restrict__ story, const float* __restrict__ E,
                 const float* __restrict__ T, float* __restrict__ msum) {
    int slot = threadIdx.x >> 5;          // 0..7
    int l    = threadIdx.x & 31;          // float4 index within row
    int row  = blockIdx.x * 8 + slot;     // t*B*M + b*M + m   (total 102,400)
    int t    = row / (Bn * Mn);
    int rem  = row - t * (Bn * Mn);
    int b    = rem / Mn;
    int m    = rem - b * Mn;

    const int* st = story + (b * Mn + m) * Sn;
    const float4* Tv = (const float4*)(T) + (size_t)(t * Mn + m) * 32;
    const float4* Et = (const float4*)(E) + (size_t)t * Vn * 32;

    float4 acc = Tv[l];
    #pragma unroll
    for (int s = 0; s < Sn; ++s) {
        float4 e = Et[(size_t)st[s] * 32 + l];
        acc.x += e.x; acc.y += e.y; acc.z += e.z; acc.w += e.w;
    }
    ((float4*)msum)[(size_t)row * 32 + l] = acc;
}

// ===========================================================================
// Hop chain from msum. grid = B x 1024 (16 waves), one block per b.
// LDS panel tileA[200][TSTR] holds the current hop table for this b.
// ===========================================================================
__global__ __launch_bounds__(1024)
void hops_kernel(const int* __restrict__ query, const float* __restrict__ E,
                 const float* __restrict__ msum, float* __restrict__ ufin) {
    __shared__ __align__(16) float tileA[Mn * TSTR];   // 104,000 B
    __shared__ float u[Dn];
    __shared__ float sc[Mn];
    __shared__ float op[1024];          // reused: score partials (4x200) / o partials (8x128)
    __shared__ float red[16];
    __shared__ float bc[2];

    const int b    = blockIdx.x;
    const int tid  = threadIdx.x;
    const int wave = tid >> 6;
    const int lane = tid & 63;
    const int d    = tid & (Dn - 1);
    const int g    = tid >> 7;             // 0..7
    const int dq   = tid >> 8;             // 0..3 (d-quarter for scores)
    const int mm   = tid & 255;            // candidate m for scores

    // Stage one table panel (200x128) for this b into tileA.
    // Batched: all <=13 global float2 loads issued before any LDS write.
    auto stage = [&](int t) {
        const float* src = msum + ((size_t)t * Bn + b) * (size_t)(Mn * Dn);
        float2 vbuf[13];
        #pragma unroll
        for (int k = 0; k < 13; ++k) {
            int r = wave + 16 * k;
            if (r < Mn)
                vbuf[k] = *(const float2*)(src + (size_t)r * Dn + 2 * lane);
        }
        #pragma unroll
        for (int k = 0; k < 13; ++k) {
            int r = wave + 16 * k;
            if (r < Mn)
                *(float2*)(tileA + r * TSTR + 2 * lane) = vbuf[k];
        }
    };

    if (tid < Dn) {
        float acc = 0.f;
        const int* q = query + b * Qn;
        #pragma unroll
        for (int j = 0; j < Qn; ++j)
            acc += E[(size_t)q[j] * Dn + tid];
        u[tid] = acc;
    }
    stage(0);
    __syncthreads();

    for (int hop = 0; hop < Hn; ++hop) {
        // scores: thread (mm, dq) computes 32-wide partial dot from LDS
        if (mm < Mn) {
            float p = 0.f;
            #pragma unroll
            for (int i = 0; i < 32; ++i)
                p += tileA[mm * TSTR + dq * 32 + i] * u[dq * 32 + i];
            op[dq * Mn + mm] = p;
        }
        __syncthreads();

        // softmax over the 200 combined scores
        float v = -FLT_MAX;
        if (tid < Mn)
            v = op[tid] + op[Mn + tid] + op[2 * Mn + tid] + op[3 * Mn + tid];
        float mx = v;
        #pragma unroll
        for (int off = 32; off; off >>= 1) mx = fmaxf(mx, __shfl_down(mx, off, 64));
        if (lane == 0) red[wave] = mx;
        __syncthreads();
        if (tid == 0) {
            float m0 = red[0];
            #pragma unroll
            for (int i = 1; i < 16; ++i) m0 = fmaxf(m0, red[i]);
            bc[0] = m0;
        }
        __syncthreads();
        float rmax = bc[0];
        float e = (tid < Mn) ? __expf(v - rmax) : 0.f;
        float sm = e;
        #pragma unroll
        for (int off = 32; off; off >>= 1) sm += __shfl_down(sm, off, 64);
        if (lane == 0) red[wave] = sm;
        __syncthreads();
        if (tid == 0) {
            float s = 0.f;
            #pragma unroll
            for (int i = 0; i < 16; ++i) s += red[i];
            bc[1] = s;
        }
        __syncthreads();
        float inv = 1.f / bc[1];
        if (tid < Mn) sc[tid] = e * inv;

        // stage next table (C for this hop, A for the next)
        stage(hop + 1);
        __syncthreads();   // covers sc write + staging

        // o[d] = sum_m proba[m] * tileA[m][d]
        float acc = 0.f;
        #pragma unroll
        for (int k = 0; k < 25; ++k) {
            int m = g + 8 * k;
            acc += sc[m] * tileA[m * TSTR + d];
        }
        op[g * Dn + d] = acc;
        __syncthreads();
        if (tid < Dn) {
            float s = 0.f;
            #pragma unroll
            for (int i = 0; i < 8; ++i) s += op[i * Dn + tid];
            u[tid] += s;
        }
        __syncthreads();
    }
    if (tid < Dn) ufin[b * Dn + tid] = u[tid];
}

// ===========================================================================
// PATH 2 (no workspace, fallback): fused hops — unchanged.
// ===========================================================================
__global__ __launch_bounds__(1024)
void hops_fused_kernel(const int* __restrict__ story, const int* __restrict__ query,
                       const float* __restrict__ E, const float* __restrict__ T,
                       float* __restrict__ ufin) {
    __shared__ __align__(16) float tile[CH * Dn];
    __shared__ float u[Dn];
    __shared__ float sc[Mn];
    __shared__ float op[8 * Dn];
    __shared__ float red[16];
    __shared__ float bc[2];

    const int b    = blockIdx.x;
    const int tid  = threadIdx.x;
    const int wave = tid >> 6;
    const int lane = tid & 63;
    const int d    = tid & (Dn - 1);
    const int g    = tid >> 7;
    const int slot = tid >> 5;
    const int l    = tid & 31;
    const int* st  = story + b * (Mn * Sn);

    if (tid < Dn) {
        float acc = 0.f;
        const int* q = query + b * Qn;
        #pragma unroll
        for (int j = 0; j < Qn; ++j)
            acc += E[(size_t)q[j] * Dn + tid];
        u[tid] = acc;
    }

    auto build = [&](int t, int base) {
        const float4* Et = (const float4*)(E) + (size_t)t * Vn * 32;
        const float4* Tt = (const float4*)(T) + (size_t)t * Mn * 32;
        for (int m = base + slot; m < base + CH; m += 32) {
            const int* sm = st + m * Sn;
            float4 acc = Tt[(size_t)m * 32 + l];
            #pragma unroll
            for (int s = 0; s < Sn; ++s) {
                float4 e = Et[(size_t)sm[s] * 32 + l];
                acc.x += e.x; acc.y += e.y; acc.z += e.z; acc.w += e.w;
            }
            ((float4*)tile)[(m - base) * 32 + l] = acc;
        }
    };
    auto scores = [&](int base) {
        for (int m = base + wave; m < base + CH; m += 16) {
            float p = tile[(m - base) * Dn + lane]      * u[lane]
                    + tile[(m - base) * Dn + lane + 64] * u[lane + 64];
            #pragma unroll
            for (int off = 32; off; off >>= 1) p += __shfl_down(p, off, 64);
            if (lane == 0) sc[m] = p;
        }
    };

    for (int hop = 0; hop < Hn; ++hop) {
        if (hop == 0) {
            build(0, 0);  __syncthreads(); scores(0);  __syncthreads();
            build(0, CH); __syncthreads(); scores(CH); __syncthreads();
        } else {
            scores(CH); __syncthreads();
            build(hop, 0); __syncthreads(); scores(0); __syncthreads();
        }

        float v = (tid < Mn) ? sc[tid] : -FLT_MAX;
        float mx = v;
        #pragma unroll
        for (int off = 32; off; off >>= 1) mx = fmaxf(mx, __shfl_down(mx, off, 64));
        if (lane == 0) red[wave] = mx;
        __syncthreads();
        if (tid == 0) {
            float m0 = red[0];
            #pragma unroll
            for (int i = 1; i < 16; ++i) m0 = fmaxf(m0, red[i]);
            bc[0] = m0;
        }
        __syncthreads();
        float rmax = bc[0];
        float e = (tid < Mn) ? __expf(v - rmax) : 0.f;
        float sm = e;
        #pragma unroll
        for (int off = 32; off; off >>= 1) sm += __shfl_down(sm, off, 64);
        if (lane == 0) red[wave] = sm;
        __syncthreads();
        if (tid == 0) {
            float s = 0.f;
            #pragma unroll
            for (int i = 0; i < 16; ++i) s += red[i];
            bc[1] = s;
        }
        __syncthreads();
        float inv = 1.f / bc[1];
        if (tid < Mn) sc[tid] = e * inv;

        float oacc = 0.f;
        build(hop + 1, 0);
        __syncthreads();
        for (int m = g; m < CH; m += 8)
            oacc += sc[m] * tile[m * Dn + d];
        __syncthreads();
        build(hop + 1, CH);
        __syncthreads();
        for (int m = CH + g; m < 2 * CH; m += 8)
            oacc += sc[m] * tile[(m - CH) * Dn + d];
        op[g * Dn + d] = oacc;
        __syncthreads();
        if (tid < Dn) {
            float s = 0.f;
            #pragma unroll
            for (int i = 0; i < 8; ++i) s += op[i * Dn + tid];
            u[tid] += s;
        }
        __syncthreads();
    }

    if (tid < Dn) ufin[b * Dn + tid] = u[tid];
}

// ===========================================================================
// ahat GEMM: C[b,v] = sum_d U[b,d]*E3[v,d].  M=128, N=50000, K=128.
// Tile 128b x 128v (391 blocks), 256 threads (16 tr x 16 tc), acc[8][8].
// Epilogue: per-(row, vtile) softmax partials {max, expsum} -> ws2.
// ===========================================================================
constexpr int KC   = 32;
constexpr int LSTR = 140;   // 128 cols + gaps
__device__ __forceinline__ int ldsCol(int c) { return c + 4 * (c >> 5); }

__global__ __launch_bounds__(256)
void ahat_gemm_kernel(const float* __restrict__ E, const float* __restrict__ ufin,
                      float* __restrict__ out, float* __restrict__ ws2) {
    __shared__ __align__(16) float uA[KC * LSTR];
    __shared__ __align__(16) float eB[KC * LSTR];
    const float* E3 = E + (size_t)Hn * Vn * Dn;

    const int tid   = threadIdx.x;
    const int tr    = tid & 15;        // b-group (8 rows each)
    const int tc    = tid >> 4;        // v-group (8 cols each)
    const int vbase = blockIdx.x * GTILE;

    const int f4 = tid & 7;            // k-float4 within chunk
    const int rr = tid >> 3;           // staging row 0..31

    float acc[8][8];
    #pragma unroll
    for (int i = 0; i < 8; ++i)
        #pragma unroll
        for (int j = 0; j < 8; ++j) acc[i][j] = 0.f;

    for (int kb = 0; kb < Dn; kb += KC) {
        #pragma unroll
        for (int i = 0; i < 4; ++i) {
            int r   = rr + 32 * i;
            int col = ldsCol(r);
            float4 uv = *(const float4*)(ufin + (size_t)r * Dn + kb + f4 * 4);
            uA[(f4 * 4 + 0) * LSTR + col] = uv.x;
            uA[(f4 * 4 + 1) * LSTR + col] = uv.y;
            uA[(f4 * 4 + 2) * LSTR + col] = uv.z;
            uA[(f4 * 4 + 3) * LSTR + col] = uv.w;
        }
        #pragma unroll
        for (int i = 0; i < 4; ++i) {
            int r  = rr + 32 * i;
            int vg = vbase + r; if (vg > Vn - 1) vg = Vn - 1;
            int col = ldsCol(r);
            float4 ev = *(const float4*)(E3 + (size_t)vg * Dn + kb + f4 * 4);
            eB[(f4 * 4 + 0) * LSTR + col] = ev.x;
            eB[(f4 * 4 + 1) * LSTR + col] = ev.y;
            eB[(f4 * 4 + 2) * LSTR + col] = ev.z;
            eB[(f4 * 4 + 3) * LSTR + col] = ev.w;
        }
        __syncthreads();
        const int ca = ldsCol(tr * 8);
        const int cb = ldsCol(tc * 8);
        #pragma unroll 2
        for (int k = 0; k < KC; ++k) {
            float4 a0 = *(const float4*)&uA[k * LSTR + ca];
            float4 a1 = *(const float4*)&uA[k * LSTR + ca + 4];
            float4 b0 = *(const float4*)&eB[k * LSTR + cb];
            float4 b1 = *(const float4*)&eB[k * LSTR + cb + 4];
            float av[8] = {a0.x, a0.y, a0.z, a0.w, a1.x, a1.y, a1.z, a1.w};
            float bv[8] = {b0.x, b0.y, b0.z, b0.w, b1.x, b1.y, b1.z, b1.w};
            #pragma unroll
            for (int i = 0; i < 8; ++i)
                #pragma unroll
                for (int j = 0; j < 8; ++j)
                    acc[i][j] += av[i] * bv[j];
        }
        __syncthreads();
    }

    const int  v0    = vbase + tc * 8;   // group fully valid or fully out
    const bool valid = v0 < Vn;
    if (valid) {
        #pragma unroll
        for (int i = 0; i < 8; ++i) {
            int bb = tr * 8 + i;
            *(float4*)(out + (size_t)bb * Vn + v0) =
                make_float4(acc[i][0], acc[i][1], acc[i][2], acc[i][3]);
            *(float4*)(out + (size_t)bb * Vn + v0 + 4) =
                make_float4(acc[i][4], acc[i][5], acc[i][6], acc[i][7]);
        }
    }

    if (ws2) {
        #pragma unroll
        for (int i = 0; i < 8; ++i) {
            float tm = -FLT_MAX, ts = 0.f;
            if (valid) {
                #pragma unroll
                for (int j = 0; j < 8; ++j) tm = fmaxf(tm, acc[i][j]);
                #pragma unroll
                for (int j = 0; j < 8; ++j) ts += __expf(acc[i][j] - tm);
            }
            uA[tc * 128 + tr * 8 + i] = tm;
            eB[tc * 128 + tr * 8 + i] = ts;
        }
        __syncthreads();
        if (tid < Bn) {
            float M = -FLT_MAX;
            #pragma unroll
            for (int t = 0; t < 16; ++t) M = fmaxf(M, uA[t * 128 + tid]);
            float S = 0.f;
            #pragma unroll
            for (int t = 0; t < 16; ++t)
                S += eB[t * 128 + tid] * __expf(uA[t * 128 + tid] - M);
            float2* w = (float2*)ws2;
            w[(size_t)blockIdx.x * Bn + tid] = make_float2(M, S);
        }
    }
}

// ===========================================================================
// Softmax merge + normalize. grid = (SMCHK, B) x 256.
// ===========================================================================
__global__ __launch_bounds__(256)
void softmax_merge_kernel(const float* __restrict__ ahat, const float* __restrict__ ws2,
                          float* __restrict__ osm) {
    __shared__ float redm[4], reds[4];
    __shared__ float bcM, bcI;

    const int ck   = blockIdx.x;
    const int b    = blockIdx.y;
    const int tid  = threadIdx.x;
    const int wave = tid >> 6;
    const int lane = tid & 63;

    float m = -FLT_MAX, s = 0.f;
    const float2* w = (const float2*)ws2;
    for (int i = tid; i < NT; i += 256) {
        float2 p = w[(size_t)i * Bn + b];
        float nm = fmaxf(m, p.x);
        s = s * __expf(m - nm) + p.y * __expf(p.x - nm);
        m = nm;
    }
    #pragma unroll
    for (int off = 32; off; off >>= 1) {
        float mo = __shfl_down(m, off, 64);
        float so = __shfl_down(s, off, 64);
        float nm = fmaxf(m, mo);
        s = s * __expf(m - nm) + so * __expf(mo - nm);
        m = nm;
    }
    if (lane == 0) { redm[wave] = m; reds[wave] = s; }
    __syncthreads();
    if (tid == 0) {
        float M = redm[0];
        #pragma unroll
        for (int i = 1; i < 4; ++i) M = fmaxf(M, redm[i]);
        float S = 0.f;
        #pragma unroll
        for (int i = 0; i < 4; ++i) S += reds[i] * __expf(redm[i] - M);
        bcM = M; bcI = 1.f / S;
    }
    __syncthreads();
    const float M   = bcM;
    const float inv = bcI;

    constexpr int C4 = Vn / SMCHK / 4;   // 1250 float4 per chunk
    const float4* row  = (const float4*)(ahat + (size_t)b * Vn) + (size_t)ck * C4;
    float4*       orow = (float4*)(osm + (size_t)b * Vn) + (size_t)ck * C4;
    for (int v = tid; v < C4; v += 256) {
        float4 x = row[v];
        orow[v] = make_float4(__expf(x.x - M) * inv, __expf(x.y - M) * inv,
                              __expf(x.z - M) * inv, __expf(x.w - M) * inv);
    }
}

// ===========================================================================
// Fallback row softmax over V=50000 (fp32), 2-pass online. grid = B x 1024.
// ===========================================================================
__global__ __launch_bounds__(1024)
void softmax_kernel(const float* __restrict__ ahat, float* __restrict__ osm) {
    __shared__ float redm[16];
    __shared__ float reds[16];
    __shared__ float bc2[2];

    int b    = blockIdx.x;
    int tid  = threadIdx.x;
    int wave = tid >> 6;
    int lane = tid & 63;

    const float4* row  = (const float4*)(ahat + (size_t)b * Vn);
    float4*       orow = (float4*)(osm + (size_t)b * Vn);
    constexpr int N4 = Vn / 4;

    float m = -FLT_MAX, s = 0.f;
    for (int v = tid; v < N4; v += 1024) {
        float4 x = row[v];
        float cm = fmaxf(fmaxf(x.x, x.y), fmaxf(x.z, x.w));
        if (cm > m) { s *= __expf(m - cm); m = cm; }
        s += __expf(x.x - m) + __expf(x.y - m) + __expf(x.z - m) + __expf(x.w - m);
    }
    #pragma unroll
    for (int off = 32; off; off >>= 1) {
        float mo = __shfl_down(m, off, 64);
        float so = __shfl_down(s, off, 64);
        float nm = fmaxf(m, mo);
        s = s * __expf(m - nm) + so * __expf(mo - nm);
        m = nm;
    }
    if (lane == 0) { redm[wave] = m; reds[wave] = s; }
    __syncthreads();
    if (tid == 0) {
        float M = redm[0];
        #pragma unroll
        for (int i = 1; i < 16; ++i) M = fmaxf(M, redm[i]);
        float S = 0.f;
        #pragma unroll
        for (int i = 0; i < 16; ++i) S += reds[i] * __expf(redm[i] - M);
        bc2[0] = M; bc2[1] = 1.f / S;
    }
    __syncthreads();
    float rmax = bc2[0];
    float inv  = bc2[1];

    for (int v = tid; v < N4; v += 1024) {
        float4 x = row[v];
        orow[v] = make_float4(__expf(x.x - rmax) * inv, __expf(x.y - rmax) * inv,
                              __expf(x.z - rmax) * inv, __expf(x.w - rmax) * inv);
    }
}

// ===========================================================================
extern "C" void kernel_launch(void* const* d_in, const int* in_sizes, int n_in,
                              void* d_out, int out_size, void* d_ws, size_t ws_size,
                              hipStream_t stream) {
    const int*   story = (const int*)d_in[0];
    const int*   query = (const int*)d_in[1];
    const float* E     = (const float*)d_in[2];
    const float* T     = (const float*)d_in[3];

    float* out  = (float*)d_out;
    float* ufin = out + (size_t)Bn * Vn;   // staged in dead second output half

    const bool haveMsum = ws_size >= MSUM_ELEMS * sizeof(float);
    const bool haveSm   = ws_size >= (MSUM_ELEMS + SMWS_ELEMS) * sizeof(float);
    float* msum = (float*)d_ws;
    float* ws2  = haveSm ? ((float*)d_ws + MSUM_ELEMS) : nullptr;

    if (haveMsum) {
        msum_kernel<<<(Hn + 1) * Bn * Mn / 8, 256, 0, stream>>>(story, E, T, msum);
        hops_kernel<<<Bn, 1024, 0, stream>>>(query, E, msum, ufin);
    } else {
        hops_fused_kernel<<<Bn, 1024, 0, stream>>>(story, query, E, T, ufin);
    }

    ahat_gemm_kernel<<<NT, 256, 0, stream>>>(E, ufin, out, ws2);

    if (ws2) {
        softmax_merge_kernel<<<dim3(SMCHK, Bn), 256, 0, stream>>>(
            out, ws2, out + (size_t)Bn * Vn);
    } else {
        softmax_kernel<<<Bn, 1024, 0, stream>>>(out, out + (size_t)Bn * Vn);
    }
}